// Round 8
// baseline (496.305 us; speedup 1.0000x reference)
//
#include <hip/hip_runtime.h>
#include <math.h>

#define NN 20000
#define NE 320000
#define NF (NN*64)
#define TB 16

typedef float v2f __attribute__((ext_vector_type(2)));

// Packed fp32 FMA, forced: d = a*b + d per 32-bit half. VOP3P v_pk_fma_f32 is
// full-rate on CDNA; __builtin_elementwise_fma was scalarizing (r3-r7 evidence:
// VALU-busy matches 2x scalar fma count, all structural changes neutral).
static __device__ __forceinline__ void pkfma(v2f& d, v2f a, v2f b){
  asm("v_pk_fma_f32 %0, %1, %2, %0" : "+v"(d) : "v"(a), "v"(b));
}

// ---------------- fused front-end: node_pre (blocks 0..1249) |
//                  receiver hist+rank & residual-weight transpose (blocks 1250..2499) ----
// h layout: h[(n*64+lane)*4 + c]  (float4 per lane, gather-friendly)
__global__ __launch_bounds__(256) void k_pre(
    const float* __restrict__ node_feats, const float* __restrict__ W_in_s,
    const float* __restrict__ W_in_v, float* __restrict__ h,
    const int* __restrict__ receivers, int* __restrict__ count, int* __restrict__ rank,
    const float* __restrict__ Ws, const float* __restrict__ Wv,
    float* __restrict__ Wst, float* __restrict__ Wvt)
{
  __shared__ float sh[16][4][64];
  if(blockIdx.x >= 1250){
    int b = blockIdx.x - 1250;
    int e = b*256 + threadIdx.x;
    rank[e] = atomicAdd(&count[receivers[e]], 1);
    if(b < 160){
      int i = b*256 + threadIdx.x;   // 0..40959
      int spec = i >> 12;
      int g = (i >> 6) & 63;
      int f = i & 63;
      Wst[spec*4096 + f*64 + g] = Ws[i];
      Wvt[spec*4096 + f*64 + g] = Wv[i];
    }
    return;
  }
  int wave = threadIdx.x >> 6, lane = threadIdx.x & 63;
  int nb = blockIdx.x*16 + wave*4;
  #pragma unroll
  for(int k=0;k<4;++k){
    int nd = wave*4 + k;
    float4 nf = *(const float4*)(node_feats + (size_t)((nb+k)*64 + lane)*4);
    sh[nd][0][lane]=nf.x; sh[nd][1][lane]=nf.y; sh[nd][2][lane]=nf.z; sh[nd][3][lane]=nf.w;
  }
  __syncthreads();
  float as[4]={0,0,0,0}, a0[4]={0,0,0,0}, a1[4]={0,0,0,0}, a2[4]={0,0,0,0};
  for(int f=0; f<64; ++f){
    float ws = W_in_s[f*64+lane], wv = W_in_v[f*64+lane];
    #pragma unroll
    for(int k=0;k<4;++k){
      int nd = wave*4 + k;
      as[k] = fmaf(sh[nd][0][f], ws, as[k]);
      a0[k] = fmaf(sh[nd][1][f], wv, a0[k]);
      a1[k] = fmaf(sh[nd][2][f], wv, a1[k]);
      a2[k] = fmaf(sh[nd][3][f], wv, a2[k]);
    }
  }
  #pragma unroll
  for(int k=0;k<4;++k){
    float4 o4; o4.x = as[k]*0.125f; o4.y = a0[k]*0.125f;
    o4.z = a1[k]*0.125f; o4.w = a2[k]*0.125f;
    *(float4*)(h + (size_t)((nb+k)*64 + lane)*4) = o4;
  }
}

// ---------------- exclusive scan over 20000 counts: 1024 threads, reg-cached ----------------
__global__ __launch_bounds__(1024) void k_scan(const int* __restrict__ count,
                                               int* __restrict__ offset)
{
  __shared__ int part[1024];
  int t = threadIdx.x;
  const int PER = 20;                      // 1024*20 = 20480 >= NN
  int base = t*PER;
  int loc[PER];
  int s = 0;
  #pragma unroll
  for(int i=0;i<PER;++i){
    int idx = base+i;
    int v = (idx < NN) ? count[idx] : 0;
    loc[i] = v; s += v;
  }
  part[t] = s;
  __syncthreads();
  for(int off=1; off<1024; off<<=1){
    int v = (t>=off) ? part[t-off] : 0;
    __syncthreads();
    part[t] += v;
    __syncthreads();
  }
  int run = t ? part[t-1] : 0;
  #pragma unroll
  for(int i=0;i<PER;++i){
    int idx = base+i;
    if(idx < NN) offset[idx] = run;
    run += loc[i];
  }
  if(t==1023) offset[NN] = part[1023];
}

// Build sorted->orig permutation: 4-B scattered writes (cheap) instead of 64-B.
__global__ __launch_bounds__(256) void k_order(
    const int* __restrict__ receivers, const int* __restrict__ offset,
    const int* __restrict__ rank, int* __restrict__ order)
{
  int e = blockIdx.x*256 + threadIdx.x;
  order[offset[receivers[e]] + rank[e]] = e;
}

// Build rec in SORTED order: coalesced 64-B writes, gathered reads (L3-absorbed).
// rec layout (16 floats): [0..2]=yhat, [3]=snd(bits), [4..11]=rad, [12]=rcv(bits), [13..15]=pad
__global__ __launch_bounds__(256) void k_scatter(
    const int* __restrict__ senders, const int* __restrict__ receivers,
    const float* __restrict__ vectors, const float* __restrict__ radial,
    const int* __restrict__ order, float* __restrict__ rec)
{
  int s = blockIdx.x*256 + threadIdx.x;
  int e = order[s];
  float vx = vectors[e*3], vy = vectors[e*3+1], vz = vectors[e*3+2];
  float rinv = rsqrtf(vx*vx + vy*vy + vz*vz + 1e-12f);
  float4 ra = *(const float4*)(radial + (size_t)e*8);
  float4 rb = *(const float4*)(radial + (size_t)e*8 + 4);
  float* rp = rec + (size_t)s*16;
  float4 w0; w0.x = vx*rinv; w0.y = vy*rinv; w0.z = vz*rinv; w0.w = __int_as_float(senders[e]);
  float4 w3; w3.x = __int_as_float(receivers[e]); w3.y = 0.f; w3.z = 0.f; w3.w = 0.f;
  *(float4*)(rp)      = w0;
  *(float4*)(rp + 4)  = ra;
  *(float4*)(rp + 8)  = rb;
  *(float4*)(rp + 12) = w3;
}

// ---------------- edge kernel: 64 edges/block, half-tiled, packed-fp32 matmul ----------------
// agg layout: agg[node*256 + c*64 + lane]  (channel-planar: contiguous atomics)
__global__ __launch_bounds__(256) void k_edge(
    const float* __restrict__ rec,
    const float* __restrict__ mlp_w1, const float* __restrict__ mlp_w2,
    const float* __restrict__ h, float* __restrict__ agg)
{
  __shared__ float recS[4][256];       // 16 edges x 16 floats per wave (wave-local)
  __shared__ float hid[4][64][18];     // [hh][t], stride 18: 8B-aligned v2f reads
  int tid = threadIdx.x;
  int wave = tid >> 6, lane = tid & 63;
  int e0 = (blockIdx.x*4 + wave)*TB;

  // stage records: 1 KB per wave in one dwordx4 (wave-local LDS, lockstep-safe)
  *(float4*)&recS[wave][lane*4] = *(const float4*)(rec + (size_t)e0*16 + lane*4);

  float wl[8];
  #pragma unroll
  for(int r=0;r<8;++r) wl[r] = mlp_w1[r*64+lane];

  // hidden = silu(rad @ w1), lane = hidden unit; store transposed [hh][t]
  #pragma unroll
  for(int t=0;t<TB;++t){
    float acc = 0.f;
    #pragma unroll
    for(int r=0;r<8;++r) acc = fmaf(recS[wave][t*16+4+r], wl[r], acc);
    hid[wave][lane][t] = acc / (1.f + __expf(-acc));
  }

  // run-accumulation state carries across halves (atomic count unchanged)
  float as_=0.f, av0=0.f, av1=0.f, av2=0.f;
  int cur = __float_as_int(recS[wave][12]);

  #pragma unroll 1
  for(int half=0; half<2; ++half){
    int tb = half*8;

    // h-gathers for this half's 8 edges: latency hides under this half's matmul
    float4 hv4[8];
    #pragma unroll
    for(int p=0;p<8;++p){
      int snd = __float_as_int(recS[wave][(tb+p)*16+3]);
      hv4[p] = *(const float4*)(h + (size_t)(snd*64 + lane)*4);
    }

    // w[j][t-pair] for 8 edges: 40 accumulator floats, forced v_pk_fma_f32
    v2f wv[5][4];
    #pragma unroll
    for(int j=0;j<5;++j)
      #pragma unroll
      for(int tp=0;tp<4;++tp) wv[j][tp] = (v2f){0.f, 0.f};

    for(int hh=0; hh<64; hh+=2){
      float b0[5], b1[5];
      #pragma unroll
      for(int j=0;j<5;++j){
        b0[j] = mlp_w2[hh*320     + j*64 + lane];
        b1[j] = mlp_w2[(hh+1)*320 + j*64 + lane];
      }
      #pragma unroll
      for(int tp=0;tp<4;++tp){
        v2f h0 = *(const v2f*)&hid[wave][hh][tb + 2*tp];
        v2f h1 = *(const v2f*)&hid[wave][hh+1][tb + 2*tp];
        #pragma unroll
        for(int j=0;j<5;++j){
          v2f bb0 = {b0[j], b0[j]};
          v2f bb1 = {b1[j], b1[j]};
          pkfma(wv[j][tp], bb0, h0);
          pkfma(wv[j][tp], bb1, h1);
        }
      }
    }

    // message build + register-run accumulation for this half
    #pragma unroll
    for(int i=0;i<8;++i){
      int t = tb + i;
      float4 hc = hv4[i];
      int rcv = __float_as_int(recS[wave][t*16+12]);
      if(rcv != cur){
        size_t ro = (size_t)cur*256 + lane;
        atomicAdd(&agg[ro],     as_);
        atomicAdd(&agg[ro+64],  av0);
        atomicAdd(&agg[ro+128], av1);
        atomicAdd(&agg[ro+192], av2);
        as_=0.f; av0=0.f; av1=0.f; av2=0.f;
        cur = rcv;
      }
      float y0=recS[wave][t*16], y1=recS[wave][t*16+1], y2=recS[wave][t*16+2];
      float ss=hc.x, sv0=hc.y, sv1=hc.z, sv2=hc.w;
      float dot = sv0*y0 + sv1*y1 + sv2*y2;
      float wt0 = wv[0][i>>1][i&1], wt1 = wv[1][i>>1][i&1];
      float wt2 = wv[2][i>>1][i&1], wt3 = wv[3][i>>1][i&1], wt4 = wv[4][i>>1][i&1];
      as_ += wt0*ss + wt1*dot;
      float w2s = wt2*ss;
      av0 += w2s*y0 + wt3*sv0 + wt4*(sv1*y2 - sv2*y1);
      av1 += w2s*y1 + wt3*sv1 + wt4*(sv2*y0 - sv0*y2);
      av2 += w2s*y2 + wt3*sv2 + wt4*(sv0*y1 - sv1*y0);
    }
  }
  size_t ro = (size_t)cur*256 + lane;
  atomicAdd(&agg[ro],     as_);
  atomicAdd(&agg[ro+64],  av0);
  atomicAdd(&agg[ro+128], av1);
  atomicAdd(&agg[ro+192], av2);
}

// ---------------- node post-pass: 4 nodes per wave ----------------
__global__ __launch_bounds__(256) void k_node_post(
  const float* __restrict__ node_feats, const int* __restrict__ specie,
  const float* __restrict__ agg,
  const float* __restrict__ Wrst, const float* __restrict__ Wrvt,
  const float* __restrict__ W_out_s, const float* __restrict__ W_out_v,
  const float* __restrict__ W_prod_s, const float* __restrict__ W_prod_v,
  const float* __restrict__ W_lin_s, const float* __restrict__ W_lin_v,
  const float* __restrict__ W_read, float* __restrict__ out_node,
  float* __restrict__ out_feats)
{
  __shared__ float shA[16][4][64];
  __shared__ float shS[16][4][64];   // node_feats first, reused for p_s/p_v
  int wave = threadIdx.x >> 6, lane = threadIdx.x & 63;
  int nb = blockIdx.x*16 + wave*4;
  #pragma unroll
  for(int k=0;k<4;++k){
    int nd = wave*4 + k;
    size_t o = (size_t)(nb+k)*256 + lane;
    shA[nd][0][lane] = agg[o]      * (1.f/16.f);
    shA[nd][1][lane] = agg[o+64]   * (1.f/16.f);
    shA[nd][2][lane] = agg[o+128]  * (1.f/16.f);
    shA[nd][3][lane] = agg[o+192]  * (1.f/16.f);
    float4 nf = *(const float4*)(node_feats + (size_t)((nb+k)*64 + lane)*4);
    shS[nd][0][lane]=nf.x; shS[nd][1][lane]=nf.y; shS[nd][2][lane]=nf.z; shS[nd][3][lane]=nf.w;
  }
  int spec[4];
  #pragma unroll
  for(int k=0;k<4;++k) spec[k] = specie[nb+k];
  __syncthreads();
  float a_s[4]={0,0,0,0}, a0[4]={0,0,0,0}, a1[4]={0,0,0,0}, a2[4]={0,0,0,0};
  float r_s[4]={0,0,0,0}, r0[4]={0,0,0,0}, r1[4]={0,0,0,0}, r2[4]={0,0,0,0};
  for(int f=0; f<64; ++f){
    float wos = W_out_s[f*64+lane], wov = W_out_v[f*64+lane];
    #pragma unroll
    for(int k=0;k<4;++k){
      int nd = wave*4 + k;
      a_s[k] = fmaf(shA[nd][0][f], wos, a_s[k]);
      a0[k]  = fmaf(shA[nd][1][f], wov, a0[k]);
      a1[k]  = fmaf(shA[nd][2][f], wov, a1[k]);
      a2[k]  = fmaf(shA[nd][3][f], wov, a2[k]);
    }
    #pragma unroll
    for(int k=0;k<4;++k){
      int nd = wave*4 + k;
      float wrs = Wrst[spec[k]*4096 + f*64 + lane];
      float wrv = Wrvt[spec[k]*4096 + f*64 + lane];
      r_s[k] = fmaf(shS[nd][0][f], wrs, r_s[k]);
      r0[k]  = fmaf(shS[nd][1][f], wrv, r0[k]);
      r1[k]  = fmaf(shS[nd][2][f], wrv, r1[k]);
      r2[k]  = fmaf(shS[nd][3][f], wrv, r2[k]);
    }
  }
  __syncthreads();
  #pragma unroll
  for(int k=0;k<4;++k){
    int nd = wave*4 + k;
    float A_s = a_s[k]*0.125f, A0 = a0[k]*0.125f, A1 = a1[k]*0.125f, A2 = a2[k]*0.125f;
    float vv = A0*A0 + A1*A1 + A2*A2;
    float as2 = A_s*A_s;
    const float* Wp = W_prod_s + spec[k]*320;
    float p_s = Wp[lane]*A_s + Wp[64+lane]*as2 + Wp[128+lane]*as2*A_s
              + Wp[192+lane]*vv + Wp[256+lane]*A_s*vv;
    const float* Wq = W_prod_v + spec[k]*256;
    float coef = Wq[lane] + Wq[64+lane]*A_s + Wq[128+lane]*as2 + Wq[192+lane]*vv;
    shS[nd][0][lane] = p_s;
    shS[nd][1][lane] = coef*A0;
    shS[nd][2][lane] = coef*A1;
    shS[nd][3][lane] = coef*A2;
  }
  __syncthreads();
  float lfs[4]={0,0,0,0}, lf0[4]={0,0,0,0}, lf1[4]={0,0,0,0}, lf2[4]={0,0,0,0};
  for(int f=0; f<64; ++f){
    float wls = W_lin_s[f*64+lane], wlv = W_lin_v[f*64+lane];
    #pragma unroll
    for(int k=0;k<4;++k){
      int nd = wave*4 + k;
      lfs[k] = fmaf(shS[nd][0][f], wls, lfs[k]);
      lf0[k] = fmaf(shS[nd][1][f], wlv, lf0[k]);
      lf1[k] = fmaf(shS[nd][2][f], wlv, lf1[k]);
      lf2[k] = fmaf(shS[nd][3][f], wlv, lf2[k]);
    }
  }
  float wr = W_read[lane];
  #pragma unroll
  for(int k=0;k<4;++k){
    int n = nb + k;
    float FS = lfs[k]*0.125f + r_s[k]*0.125f;
    float F0 = lf0[k]*0.125f + r0[k]*0.125f;
    float F1 = lf1[k]*0.125f + r1[k]*0.125f;
    float F2 = lf2[k]*0.125f + r2[k]*0.125f;
    float x = FS * wr;
    #pragma unroll
    for(int off=32; off; off>>=1) x += __shfl_down(x, off);
    if(lane==0) out_node[n] = x*0.125f;
    float4 o4; o4.x=FS; o4.y=F0; o4.z=F1; o4.w=F2;
    *(float4*)(out_feats + (size_t)(n*64+lane)*4) = o4;
  }
}

extern "C" void kernel_launch(void* const* d_in, const int* in_sizes, int n_in,
                              void* d_out, int out_size, void* d_ws, size_t ws_size,
                              hipStream_t stream) {
  const float* vectors    = (const float*)d_in[0];
  const float* node_feats = (const float*)d_in[1];
  const int*   node_specie= (const int*)  d_in[2];
  const float* radial     = (const float*)d_in[3];
  const int*   senders    = (const int*)  d_in[4];
  const int*   receivers  = (const int*)  d_in[5];
  const float* W_res_s    = (const float*)d_in[6];
  const float* W_res_v    = (const float*)d_in[7];
  const float* W_in_s     = (const float*)d_in[8];
  const float* W_in_v     = (const float*)d_in[9];
  const float* mlp_w1     = (const float*)d_in[10];
  const float* mlp_w2     = (const float*)d_in[11];
  const float* W_out_s    = (const float*)d_in[12];
  const float* W_out_v    = (const float*)d_in[13];
  const float* W_prod_s   = (const float*)d_in[14];
  const float* W_prod_v   = (const float*)d_in[15];
  const float* W_lin_s    = (const float*)d_in[16];
  const float* W_lin_v    = (const float*)d_in[17];
  const float* W_read     = (const float*)d_in[18];

  float* ws   = (float*)d_ws;
  float* h    = ws;                          // 4*NF floats, [(n*64+lane)*4+c]
  float* agg  = ws + 4*(size_t)NF;           // 4*NF floats, [n*256 + c*64 + lane]
  float* Wrst = ws + 8*(size_t)NF;           // 40960
  float* Wrvt = Wrst + 40960;                // 40960
  float* rec  = Wrvt + 40960;                // 16*NE floats (64 B per edge)
  int*   rank   = (int*)(rec + 16*(size_t)NE); // NE
  int*   order  = rank + NE;                 // NE
  int*   offset = order + NE;                // NN+1
  int*   count  = offset + NN + 1;           // NN

  hipMemsetAsync(agg,   0, (size_t)4*NF*sizeof(float), stream);
  hipMemsetAsync(count, 0, (size_t)NN*sizeof(int), stream);
  k_pre<<<2500, 256, 0, stream>>>(node_feats, W_in_s, W_in_v, h,
                                  receivers, count, rank,
                                  W_res_s, W_res_v, Wrst, Wrvt);
  k_scan   <<<1,     1024, 0, stream>>>(count, offset);
  k_order  <<<NE/256, 256, 0, stream>>>(receivers, offset, rank, order);
  k_scatter<<<NE/256, 256, 0, stream>>>(senders, receivers, vectors, radial,
                                        order, rec);
  k_edge<<<NE/64, 256, 0, stream>>>(rec, mlp_w1, mlp_w2, h, agg);
  k_node_post<<<NN/16, 256, 0, stream>>>(node_feats, node_specie, agg,
                                         Wrst, Wrvt, W_out_s, W_out_v,
                                         W_prod_s, W_prod_v, W_lin_s, W_lin_v,
                                         W_read, (float*)d_out, (float*)d_out + NN);
}

// Round 9
// 474.313 us; speedup vs baseline: 1.0464x; 1.0464x over previous
//
#include <hip/hip_runtime.h>
#include <math.h>

#define NN 20000
#define NE 320000
#define NF (NN*64)
#define TB 16

typedef float v2f __attribute__((ext_vector_type(2)));

#if __has_builtin(__builtin_elementwise_fma)
#define PKFMA(a,b,c) __builtin_elementwise_fma(a,b,c)
#else
static __device__ __forceinline__ v2f PKFMA(v2f a, v2f b, v2f c){
  v2f r; r.x = fmaf(a.x,b.x,c.x); r.y = fmaf(a.y,b.y,c.y); return r;
}
#endif

// ---------------- fused front-end: node_pre 8/wave (blocks 0..624) |
//                  receiver hist+rank & residual-weight transpose (blocks 625..1874) ----
// h layout: h[(n*64+lane)*4 + c]  (float4 per lane, gather-friendly)
__global__ __launch_bounds__(256) void k_pre(
    const float* __restrict__ node_feats, const float* __restrict__ W_in_s,
    const float* __restrict__ W_in_v, float* __restrict__ h,
    const int* __restrict__ receivers, int* __restrict__ count, int* __restrict__ rank,
    const float* __restrict__ Ws, const float* __restrict__ Wv,
    float* __restrict__ Wst, float* __restrict__ Wvt)
{
  __shared__ float sh[32][4][64];
  if(blockIdx.x >= 625){
    int b = blockIdx.x - 625;
    int e = b*256 + threadIdx.x;
    rank[e] = atomicAdd(&count[receivers[e]], 1);
    if(b < 160){
      int i = b*256 + threadIdx.x;   // 0..40959
      int spec = i >> 12;
      int g = (i >> 6) & 63;
      int f = i & 63;
      Wst[spec*4096 + f*64 + g] = Ws[i];
      Wvt[spec*4096 + f*64 + g] = Wv[i];
    }
    return;
  }
  int wave = threadIdx.x >> 6, lane = threadIdx.x & 63;
  int nb = blockIdx.x*32 + wave*8;
  #pragma unroll
  for(int k=0;k<8;++k){
    int nd = wave*8 + k;
    float4 nf = *(const float4*)(node_feats + (size_t)((nb+k)*64 + lane)*4);
    sh[nd][0][lane]=nf.x; sh[nd][1][lane]=nf.y; sh[nd][2][lane]=nf.z; sh[nd][3][lane]=nf.w;
  }
  __syncthreads();
  float as[8]={0,0,0,0,0,0,0,0}, a0[8]={0,0,0,0,0,0,0,0};
  float a1[8]={0,0,0,0,0,0,0,0}, a2[8]={0,0,0,0,0,0,0,0};
  for(int f=0; f<64; ++f){
    float ws = W_in_s[f*64+lane], wv = W_in_v[f*64+lane];
    #pragma unroll
    for(int k=0;k<8;++k){
      int nd = wave*8 + k;
      as[k] = fmaf(sh[nd][0][f], ws, as[k]);
      a0[k] = fmaf(sh[nd][1][f], wv, a0[k]);
      a1[k] = fmaf(sh[nd][2][f], wv, a1[k]);
      a2[k] = fmaf(sh[nd][3][f], wv, a2[k]);
    }
  }
  #pragma unroll
  for(int k=0;k<8;++k){
    float4 o4; o4.x = as[k]*0.125f; o4.y = a0[k]*0.125f;
    o4.z = a1[k]*0.125f; o4.w = a2[k]*0.125f;
    *(float4*)(h + (size_t)((nb+k)*64 + lane)*4) = o4;
  }
}

// ---------------- exclusive scan over 20000 counts: 1024 threads, reg-cached ----------------
__global__ __launch_bounds__(1024) void k_scan(const int* __restrict__ count,
                                               int* __restrict__ offset)
{
  __shared__ int part[1024];
  int t = threadIdx.x;
  const int PER = 20;                      // 1024*20 = 20480 >= NN
  int base = t*PER;
  int loc[PER];
  int s = 0;
  #pragma unroll
  for(int i=0;i<PER;++i){
    int idx = base+i;
    int v = (idx < NN) ? count[idx] : 0;
    loc[i] = v; s += v;
  }
  part[t] = s;
  __syncthreads();
  for(int off=1; off<1024; off<<=1){
    int v = (t>=off) ? part[t-off] : 0;
    __syncthreads();
    part[t] += v;
    __syncthreads();
  }
  int run = t ? part[t-1] : 0;
  #pragma unroll
  for(int i=0;i<PER;++i){
    int idx = base+i;
    if(idx < NN) offset[idx] = run;
    run += loc[i];
  }
  if(t==1023) offset[NN] = part[1023];
}

// Scatter edge data into one 64-B record per edge (receiver-sorted).
// rec layout (16 floats): [0..2]=yhat, [3]=snd(bits), [4..11]=rad, [12]=rcv(bits), [13..15]=pad
__global__ __launch_bounds__(256) void k_scatter(
    const int* __restrict__ senders, const int* __restrict__ receivers,
    const float* __restrict__ vectors, const float* __restrict__ radial,
    const int* __restrict__ offset, const int* __restrict__ rank,
    float* __restrict__ rec)
{
  int e = blockIdx.x*256 + threadIdx.x;
  int r = receivers[e];
  int slot = offset[r] + rank[e];
  float vx = vectors[e*3], vy = vectors[e*3+1], vz = vectors[e*3+2];
  float rinv = rsqrtf(vx*vx + vy*vy + vz*vz + 1e-12f);
  float4 ra = *(const float4*)(radial + (size_t)e*8);
  float4 rb = *(const float4*)(radial + (size_t)e*8 + 4);
  float* rp = rec + (size_t)slot*16;
  float4 w0; w0.x = vx*rinv; w0.y = vy*rinv; w0.z = vz*rinv; w0.w = __int_as_float(senders[e]);
  float4 w3; w3.x = __int_as_float(r); w3.y = 0.f; w3.z = 0.f; w3.w = 0.f;
  *(float4*)(rp)      = w0;
  *(float4*)(rp + 4)  = ra;
  *(float4*)(rp + 8)  = rb;
  *(float4*)(rp + 12) = w3;
}

// ---------------- edge kernel: r3-exact (measured 215 us) ----------------
// agg layout: agg[node*256 + c*64 + lane]  (channel-planar: contiguous atomics)
__global__ __launch_bounds__(256) void k_edge(
    const float* __restrict__ rec,
    const float* __restrict__ mlp_w1, const float* __restrict__ mlp_w2,
    const float* __restrict__ h, float* __restrict__ agg)
{
  __shared__ float recS[4][256];        // 16 edges x 16 floats, wave-local
  __shared__ float hid[4][64][20];      // [hh][t], stride 20; reads broadcast
  int tid = threadIdx.x;
  int wave = tid >> 6, lane = tid & 63;
  int e0 = (blockIdx.x*4 + wave)*TB;

  // stage records: 1 KB per wave in one dwordx4 (wave-local LDS, lockstep-safe)
  *(float4*)&recS[wave][lane*4] = *(const float4*)(rec + (size_t)e0*16 + lane*4);

  float wl[8];
  #pragma unroll
  for(int r=0;r<8;++r) wl[r] = mlp_w1[r*64+lane];

  // hidden = silu(rad @ w1), lane = hidden unit; store transposed [hh][t]
  #pragma unroll
  for(int t=0;t<TB;++t){
    float acc = 0.f;
    #pragma unroll
    for(int r=0;r<8;++r) acc = fmaf(recS[wave][t*16+4+r], wl[r], acc);
    hid[wave][lane][t] = acc / (1.f + __expf(-acc));
  }

  // w[j][t-pair] = sum_h hid[h][t-pair] * w2[h][j*64+lane]  -- packed fp32
  v2f wv[5][8];
  #pragma unroll
  for(int j=0;j<5;++j)
    #pragma unroll
    for(int tp=0;tp<8;++tp) wv[j][tp] = (v2f){0.f, 0.f};
  const float* w2p = mlp_w2 + lane;
  for(int hh=0; hh<64; ++hh){
    float b[5];
    #pragma unroll
    for(int j=0;j<5;++j) b[j] = w2p[hh*320 + j*64];
    v2f hv[8];
    #pragma unroll
    for(int tp=0;tp<8;++tp) hv[tp] = *(const v2f*)&hid[wave][hh][2*tp];
    #pragma unroll
    for(int j=0;j<5;++j){
      v2f bb = {b[j], b[j]};
      #pragma unroll
      for(int tp=0;tp<8;++tp) wv[j][tp] = PKFMA(bb, hv[tp], wv[j][tp]);
    }
  }

  // message build + register-run accumulation; h gathered as one float4, 4-deep pipeline
  float4 hv4[4];
  #pragma unroll
  for(int p=0;p<4;++p){
    int snd = __float_as_int(recS[wave][p*16+3]);
    hv4[p] = *(const float4*)(h + (size_t)(snd*64 + lane)*4);
  }

  float as_=0.f, av0=0.f, av1=0.f, av2=0.f;
  int cur = __float_as_int(recS[wave][12]);
  #pragma unroll
  for(int t=0;t<TB;++t){
    float4 hc = hv4[t&3];
    if(t+4 < TB){
      int snd = __float_as_int(recS[wave][(t+4)*16+3]);
      hv4[t&3] = *(const float4*)(h + (size_t)(snd*64 + lane)*4);
    }
    int rcv = __float_as_int(recS[wave][t*16+12]);
    if(rcv != cur){
      size_t ro = (size_t)cur*256 + lane;
      atomicAdd(&agg[ro],     as_);
      atomicAdd(&agg[ro+64],  av0);
      atomicAdd(&agg[ro+128], av1);
      atomicAdd(&agg[ro+192], av2);
      as_=0.f; av0=0.f; av1=0.f; av2=0.f;
      cur = rcv;
    }
    float y0=recS[wave][t*16], y1=recS[wave][t*16+1], y2=recS[wave][t*16+2];
    float ss=hc.x, sv0=hc.y, sv1=hc.z, sv2=hc.w;
    float dot = sv0*y0 + sv1*y1 + sv2*y2;
    float wt0 = wv[0][t>>1][t&1], wt1 = wv[1][t>>1][t&1];
    float wt2 = wv[2][t>>1][t&1], wt3 = wv[3][t>>1][t&1], wt4 = wv[4][t>>1][t&1];
    as_ += wt0*ss + wt1*dot;
    float w2s = wt2*ss;
    av0 += w2s*y0 + wt3*sv0 + wt4*(sv1*y2 - sv2*y1);
    av1 += w2s*y1 + wt3*sv1 + wt4*(sv2*y0 - sv0*y2);
    av2 += w2s*y2 + wt3*sv2 + wt4*(sv0*y1 - sv1*y0);
  }
  size_t ro = (size_t)cur*256 + lane;
  atomicAdd(&agg[ro],     as_);
  atomicAdd(&agg[ro+64],  av0);
  atomicAdd(&agg[ro+128], av1);
  atomicAdd(&agg[ro+192], av2);
}

// ---------------- node post-pass: 8 nodes per wave (weights amortized 2x) ----------------
__global__ __launch_bounds__(256) void k_node_post(
  const float* __restrict__ node_feats, const int* __restrict__ specie,
  const float* __restrict__ agg,
  const float* __restrict__ Wrst, const float* __restrict__ Wrvt,
  const float* __restrict__ W_out_s, const float* __restrict__ W_out_v,
  const float* __restrict__ W_prod_s, const float* __restrict__ W_prod_v,
  const float* __restrict__ W_lin_s, const float* __restrict__ W_lin_v,
  const float* __restrict__ W_read, float* __restrict__ out_node,
  float* __restrict__ out_feats)
{
  __shared__ float shA[32][4][64];
  __shared__ float shS[32][4][64];   // node_feats first, reused for p_s/p_v
  int wave = threadIdx.x >> 6, lane = threadIdx.x & 63;
  int nb = blockIdx.x*32 + wave*8;
  #pragma unroll
  for(int k=0;k<8;++k){
    int nd = wave*8 + k;
    size_t o = (size_t)(nb+k)*256 + lane;
    shA[nd][0][lane] = agg[o]      * (1.f/16.f);
    shA[nd][1][lane] = agg[o+64]   * (1.f/16.f);
    shA[nd][2][lane] = agg[o+128]  * (1.f/16.f);
    shA[nd][3][lane] = agg[o+192]  * (1.f/16.f);
    float4 nf = *(const float4*)(node_feats + (size_t)((nb+k)*64 + lane)*4);
    shS[nd][0][lane]=nf.x; shS[nd][1][lane]=nf.y; shS[nd][2][lane]=nf.z; shS[nd][3][lane]=nf.w;
  }
  int spec[8];
  #pragma unroll
  for(int k=0;k<8;++k) spec[k] = specie[nb+k];
  __syncthreads();
  float a_s[8]={0,0,0,0,0,0,0,0}, a0[8]={0,0,0,0,0,0,0,0};
  float a1[8]={0,0,0,0,0,0,0,0}, a2[8]={0,0,0,0,0,0,0,0};
  float r_s[8]={0,0,0,0,0,0,0,0}, r0[8]={0,0,0,0,0,0,0,0};
  float r1[8]={0,0,0,0,0,0,0,0}, r2[8]={0,0,0,0,0,0,0,0};
  for(int f=0; f<64; ++f){
    float wos = W_out_s[f*64+lane], wov = W_out_v[f*64+lane];
    #pragma unroll
    for(int k=0;k<8;++k){
      int nd = wave*8 + k;
      a_s[k] = fmaf(shA[nd][0][f], wos, a_s[k]);
      a0[k]  = fmaf(shA[nd][1][f], wov, a0[k]);
      a1[k]  = fmaf(shA[nd][2][f], wov, a1[k]);
      a2[k]  = fmaf(shA[nd][3][f], wov, a2[k]);
    }
    #pragma unroll
    for(int k=0;k<8;++k){
      int nd = wave*8 + k;
      float wrs = Wrst[spec[k]*4096 + f*64 + lane];
      float wrv = Wrvt[spec[k]*4096 + f*64 + lane];
      r_s[k] = fmaf(shS[nd][0][f], wrs, r_s[k]);
      r0[k]  = fmaf(shS[nd][1][f], wrv, r0[k]);
      r1[k]  = fmaf(shS[nd][2][f], wrv, r1[k]);
      r2[k]  = fmaf(shS[nd][3][f], wrv, r2[k]);
    }
  }
  __syncthreads();
  #pragma unroll
  for(int k=0;k<8;++k){
    int nd = wave*8 + k;
    float A_s = a_s[k]*0.125f, A0 = a0[k]*0.125f, A1 = a1[k]*0.125f, A2 = a2[k]*0.125f;
    float vv = A0*A0 + A1*A1 + A2*A2;
    float as2 = A_s*A_s;
    const float* Wp = W_prod_s + spec[k]*320;
    float p_s = Wp[lane]*A_s + Wp[64+lane]*as2 + Wp[128+lane]*as2*A_s
              + Wp[192+lane]*vv + Wp[256+lane]*A_s*vv;
    const float* Wq = W_prod_v + spec[k]*256;
    float coef = Wq[lane] + Wq[64+lane]*A_s + Wq[128+lane]*as2 + Wq[192+lane]*vv;
    shS[nd][0][lane] = p_s;
    shS[nd][1][lane] = coef*A0;
    shS[nd][2][lane] = coef*A1;
    shS[nd][3][lane] = coef*A2;
  }
  __syncthreads();
  float lfs[8]={0,0,0,0,0,0,0,0}, lf0[8]={0,0,0,0,0,0,0,0};
  float lf1[8]={0,0,0,0,0,0,0,0}, lf2[8]={0,0,0,0,0,0,0,0};
  for(int f=0; f<64; ++f){
    float wls = W_lin_s[f*64+lane], wlv = W_lin_v[f*64+lane];
    #pragma unroll
    for(int k=0;k<8;++k){
      int nd = wave*8 + k;
      lfs[k] = fmaf(shS[nd][0][f], wls, lfs[k]);
      lf0[k] = fmaf(shS[nd][1][f], wlv, lf0[k]);
      lf1[k] = fmaf(shS[nd][2][f], wlv, lf1[k]);
      lf2[k] = fmaf(shS[nd][3][f], wlv, lf2[k]);
    }
  }
  float wr = W_read[lane];
  #pragma unroll
  for(int k=0;k<8;++k){
    int n = nb + k;
    float FS = lfs[k]*0.125f + r_s[k]*0.125f;
    float F0 = lf0[k]*0.125f + r0[k]*0.125f;
    float F1 = lf1[k]*0.125f + r1[k]*0.125f;
    float F2 = lf2[k]*0.125f + r2[k]*0.125f;
    float x = FS * wr;
    #pragma unroll
    for(int off=32; off; off>>=1) x += __shfl_down(x, off);
    if(lane==0) out_node[n] = x*0.125f;
    float4 o4; o4.x=FS; o4.y=F0; o4.z=F1; o4.w=F2;
    *(float4*)(out_feats + (size_t)(n*64+lane)*4) = o4;
  }
}

extern "C" void kernel_launch(void* const* d_in, const int* in_sizes, int n_in,
                              void* d_out, int out_size, void* d_ws, size_t ws_size,
                              hipStream_t stream) {
  const float* vectors    = (const float*)d_in[0];
  const float* node_feats = (const float*)d_in[1];
  const int*   node_specie= (const int*)  d_in[2];
  const float* radial     = (const float*)d_in[3];
  const int*   senders    = (const int*)  d_in[4];
  const int*   receivers  = (const int*)  d_in[5];
  const float* W_res_s    = (const float*)d_in[6];
  const float* W_res_v    = (const float*)d_in[7];
  const float* W_in_s     = (const float*)d_in[8];
  const float* W_in_v     = (const float*)d_in[9];
  const float* mlp_w1     = (const float*)d_in[10];
  const float* mlp_w2     = (const float*)d_in[11];
  const float* W_out_s    = (const float*)d_in[12];
  const float* W_out_v    = (const float*)d_in[13];
  const float* W_prod_s   = (const float*)d_in[14];
  const float* W_prod_v   = (const float*)d_in[15];
  const float* W_lin_s    = (const float*)d_in[16];
  const float* W_lin_v    = (const float*)d_in[17];
  const float* W_read     = (const float*)d_in[18];

  float* ws   = (float*)d_ws;
  float* h    = ws;                          // 4*NF floats, [(n*64+lane)*4+c]
  float* agg  = ws + 4*(size_t)NF;           // 4*NF floats, [n*256 + c*64 + lane]
  float* Wrst = ws + 8*(size_t)NF;           // 40960
  float* Wrvt = Wrst + 40960;                // 40960
  float* rec  = Wrvt + 40960;                // 16*NE floats (64 B per edge)
  int*   rank   = (int*)(rec + 16*(size_t)NE); // NE
  int*   offset = rank + NE;                 // NN+1
  int*   count  = offset + NN + 1;           // NN

  hipMemsetAsync(agg,   0, (size_t)4*NF*sizeof(float), stream);
  hipMemsetAsync(count, 0, (size_t)NN*sizeof(int), stream);
  k_pre<<<1875, 256, 0, stream>>>(node_feats, W_in_s, W_in_v, h,
                                  receivers, count, rank,
                                  W_res_s, W_res_v, Wrst, Wrvt);
  k_scan   <<<1,     1024, 0, stream>>>(count, offset);
  k_scatter<<<NE/256, 256, 0, stream>>>(senders, receivers, vectors, radial,
                                        offset, rank, rec);
  k_edge<<<NE/64, 256, 0, stream>>>(rec, mlp_w1, mlp_w2, h, agg);
  k_node_post<<<625, 256, 0, stream>>>(node_feats, node_specie, agg,
                                       Wrst, Wrvt, W_out_s, W_out_v,
                                       W_prod_s, W_prod_v, W_lin_s, W_lin_v,
                                       W_read, (float*)d_out, (float*)d_out + NN);
}

// Round 10
// 472.111 us; speedup vs baseline: 1.0512x; 1.0047x over previous
//
#include <hip/hip_runtime.h>
#include <math.h>

#define NN 20000
#define NE 320000
#define NF (NN*64)
#define TB 16

typedef float v2f __attribute__((ext_vector_type(2)));

#if __has_builtin(__builtin_elementwise_fma)
#define PKFMA(a,b,c) __builtin_elementwise_fma(a,b,c)
#else
static __device__ __forceinline__ v2f PKFMA(v2f a, v2f b, v2f c){
  v2f r; r.x = fmaf(a.x,b.x,c.x); r.y = fmaf(a.y,b.y,c.y); return r;
}
#endif

// ---------------- fused front-end ----------------
// blocks 0..1249   : node_pre, 4 nodes/wave (r7-proven)
// blocks 1250..2499: receiver hist+rank; b<160 also residual-W transpose;
//                    b in [160,288) also w2 repack -> w2r[hh][lane][8]
__global__ __launch_bounds__(256) void k_pre(
    const float* __restrict__ node_feats, const float* __restrict__ W_in_s,
    const float* __restrict__ W_in_v, float* __restrict__ h,
    const int* __restrict__ receivers, int* __restrict__ count, int* __restrict__ rank,
    const float* __restrict__ Ws, const float* __restrict__ Wv,
    float* __restrict__ Wst, float* __restrict__ Wvt,
    const float* __restrict__ w2, float* __restrict__ w2r)
{
  __shared__ float sh[16][4][64];
  if(blockIdx.x >= 1250){
    int b = blockIdx.x - 1250;
    int e = b*256 + threadIdx.x;
    rank[e] = atomicAdd(&count[receivers[e]], 1);
    if(b < 160){
      int i = b*256 + threadIdx.x;   // 0..40959
      int spec = i >> 12;
      int g = (i >> 6) & 63;
      int f = i & 63;
      Wst[spec*4096 + f*64 + g] = Ws[i];
      Wvt[spec*4096 + f*64 + g] = Wv[i];
    } else if(b < 288){
      int i = (b-160)*256 + threadIdx.x;  // 0..32767
      int hh = i >> 9;
      int r  = i & 511;
      int ln = r >> 3;
      int j  = r & 7;
      w2r[i] = (j < 5) ? w2[hh*320 + j*64 + ln] : 0.f;
    }
    return;
  }
  int wave = threadIdx.x >> 6, lane = threadIdx.x & 63;
  int nb = blockIdx.x*16 + wave*4;
  #pragma unroll
  for(int k=0;k<4;++k){
    int nd = wave*4 + k;
    float4 nf = *(const float4*)(node_feats + (size_t)((nb+k)*64 + lane)*4);
    sh[nd][0][lane]=nf.x; sh[nd][1][lane]=nf.y; sh[nd][2][lane]=nf.z; sh[nd][3][lane]=nf.w;
  }
  __syncthreads();
  float as[4]={0,0,0,0}, a0[4]={0,0,0,0}, a1[4]={0,0,0,0}, a2[4]={0,0,0,0};
  for(int f=0; f<64; ++f){
    float ws = W_in_s[f*64+lane], wv = W_in_v[f*64+lane];
    #pragma unroll
    for(int k=0;k<4;++k){
      int nd = wave*4 + k;
      as[k] = fmaf(sh[nd][0][f], ws, as[k]);
      a0[k] = fmaf(sh[nd][1][f], wv, a0[k]);
      a1[k] = fmaf(sh[nd][2][f], wv, a1[k]);
      a2[k] = fmaf(sh[nd][3][f], wv, a2[k]);
    }
  }
  #pragma unroll
  for(int k=0;k<4;++k){
    float4 o4; o4.x = as[k]*0.125f; o4.y = a0[k]*0.125f;
    o4.z = a1[k]*0.125f; o4.w = a2[k]*0.125f;
    *(float4*)(h + (size_t)((nb+k)*64 + lane)*4) = o4;
  }
}

// ---------------- exclusive scan over 20000 counts: 1024 threads, reg-cached ----------------
__global__ __launch_bounds__(1024) void k_scan(const int* __restrict__ count,
                                               int* __restrict__ offset)
{
  __shared__ int part[1024];
  int t = threadIdx.x;
  const int PER = 20;                      // 1024*20 = 20480 >= NN
  int base = t*PER;
  int loc[PER];
  int s = 0;
  #pragma unroll
  for(int i=0;i<PER;++i){
    int idx = base+i;
    int v = (idx < NN) ? count[idx] : 0;
    loc[i] = v; s += v;
  }
  part[t] = s;
  __syncthreads();
  for(int off=1; off<1024; off<<=1){
    int v = (t>=off) ? part[t-off] : 0;
    __syncthreads();
    part[t] += v;
    __syncthreads();
  }
  int run = t ? part[t-1] : 0;
  #pragma unroll
  for(int i=0;i<PER;++i){
    int idx = base+i;
    if(idx < NN) offset[idx] = run;
    run += loc[i];
  }
  if(t==1023) offset[NN] = part[1023];
}

// Scatter edge data into one 64-B record per edge (receiver-sorted).
// rec layout (16 floats): [0..2]=yhat, [3]=snd(bits), [4..11]=rad, [12]=rcv(bits), [13..15]=pad
__global__ __launch_bounds__(256) void k_scatter(
    const int* __restrict__ senders, const int* __restrict__ receivers,
    const float* __restrict__ vectors, const float* __restrict__ radial,
    const int* __restrict__ offset, const int* __restrict__ rank,
    float* __restrict__ rec)
{
  int e = blockIdx.x*256 + threadIdx.x;
  int r = receivers[e];
  int slot = offset[r] + rank[e];
  float vx = vectors[e*3], vy = vectors[e*3+1], vz = vectors[e*3+2];
  float rinv = rsqrtf(vx*vx + vy*vy + vz*vz + 1e-12f);
  float4 ra = *(const float4*)(radial + (size_t)e*8);
  float4 rb = *(const float4*)(radial + (size_t)e*8 + 4);
  float* rp = rec + (size_t)slot*16;
  float4 w0; w0.x = vx*rinv; w0.y = vy*rinv; w0.z = vz*rinv; w0.w = __int_as_float(senders[e]);
  float4 w3; w3.x = __int_as_float(r); w3.y = 0.f; w3.z = 0.f; w3.w = 0.f;
  *(float4*)(rp)      = w0;
  *(float4*)(rp + 4)  = ra;
  *(float4*)(rp + 8)  = rb;
  *(float4*)(rp + 12) = w3;
}

// ---------------- edge kernel: r3 structure, reduced op-mix in the hot loop ----------------
// Per hh: VMEM 5->2 (w2r packed float4+float), LDS 8x b64 -> 4x b128 (rows 80B stride,
// 16B aligned). Same PKFMA order -> bit-identical output.
// agg layout: agg[node*256 + c*64 + lane]  (channel-planar: contiguous atomics)
__global__ __launch_bounds__(256) void k_edge(
    const float* __restrict__ rec,
    const float* __restrict__ mlp_w1, const float* __restrict__ w2r,
    const float* __restrict__ h, float* __restrict__ agg)
{
  __shared__ float recS[4][256];        // 16 edges x 16 floats, wave-local
  __shared__ float hid[4][64][20];      // [hh][t], stride 20 (80B, 16B-aligned rows)
  int tid = threadIdx.x;
  int wave = tid >> 6, lane = tid & 63;
  int e0 = (blockIdx.x*4 + wave)*TB;

  // stage records: 1 KB per wave in one dwordx4 (wave-local LDS, lockstep-safe)
  *(float4*)&recS[wave][lane*4] = *(const float4*)(rec + (size_t)e0*16 + lane*4);

  float wl[8];
  #pragma unroll
  for(int r=0;r<8;++r) wl[r] = mlp_w1[r*64+lane];

  // hidden = silu(rad @ w1), lane = hidden unit; store transposed [hh][t]
  #pragma unroll
  for(int t=0;t<TB;++t){
    float acc = 0.f;
    #pragma unroll
    for(int r=0;r<8;++r) acc = fmaf(recS[wave][t*16+4+r], wl[r], acc);
    hid[wave][lane][t] = acc / (1.f + __expf(-acc));
  }

  // w[j][t-pair] = sum_h hid[h][t-pair] * w2[h][j*64+lane]  -- packed fp32
  v2f wv[5][8];
  #pragma unroll
  for(int j=0;j<5;++j)
    #pragma unroll
    for(int tp=0;tp<8;++tp) wv[j][tp] = (v2f){0.f, 0.f};
  const float* w2p = w2r + (size_t)lane*8;
  for(int hh=0; hh<64; ++hh){
    float4 b04 = *(const float4*)(w2p + hh*512);
    float  b4  = w2p[hh*512 + 4];
    float b[5] = {b04.x, b04.y, b04.z, b04.w, b4};
    float4 q0 = *(const float4*)&hid[wave][hh][0];
    float4 q1 = *(const float4*)&hid[wave][hh][4];
    float4 q2 = *(const float4*)&hid[wave][hh][8];
    float4 q3 = *(const float4*)&hid[wave][hh][12];
    v2f hv[8];
    hv[0] = (v2f){q0.x, q0.y}; hv[1] = (v2f){q0.z, q0.w};
    hv[2] = (v2f){q1.x, q1.y}; hv[3] = (v2f){q1.z, q1.w};
    hv[4] = (v2f){q2.x, q2.y}; hv[5] = (v2f){q2.z, q2.w};
    hv[6] = (v2f){q3.x, q3.y}; hv[7] = (v2f){q3.z, q3.w};
    #pragma unroll
    for(int j=0;j<5;++j){
      v2f bb = {b[j], b[j]};
      #pragma unroll
      for(int tp=0;tp<8;++tp) wv[j][tp] = PKFMA(bb, hv[tp], wv[j][tp]);
    }
  }

  // message build + register-run accumulation; h gathered as one float4, 4-deep pipeline
  float4 hv4[4];
  #pragma unroll
  for(int p=0;p<4;++p){
    int snd = __float_as_int(recS[wave][p*16+3]);
    hv4[p] = *(const float4*)(h + (size_t)(snd*64 + lane)*4);
  }

  float as_=0.f, av0=0.f, av1=0.f, av2=0.f;
  int cur = __float_as_int(recS[wave][12]);
  #pragma unroll
  for(int t=0;t<TB;++t){
    float4 hc = hv4[t&3];
    if(t+4 < TB){
      int snd = __float_as_int(recS[wave][(t+4)*16+3]);
      hv4[t&3] = *(const float4*)(h + (size_t)(snd*64 + lane)*4);
    }
    int rcv = __float_as_int(recS[wave][t*16+12]);
    if(rcv != cur){
      size_t ro = (size_t)cur*256 + lane;
      atomicAdd(&agg[ro],     as_);
      atomicAdd(&agg[ro+64],  av0);
      atomicAdd(&agg[ro+128], av1);
      atomicAdd(&agg[ro+192], av2);
      as_=0.f; av0=0.f; av1=0.f; av2=0.f;
      cur = rcv;
    }
    float y0=recS[wave][t*16], y1=recS[wave][t*16+1], y2=recS[wave][t*16+2];
    float ss=hc.x, sv0=hc.y, sv1=hc.z, sv2=hc.w;
    float dot = sv0*y0 + sv1*y1 + sv2*y2;
    float wt0 = wv[0][t>>1][t&1], wt1 = wv[1][t>>1][t&1];
    float wt2 = wv[2][t>>1][t&1], wt3 = wv[3][t>>1][t&1], wt4 = wv[4][t>>1][t&1];
    as_ += wt0*ss + wt1*dot;
    float w2s = wt2*ss;
    av0 += w2s*y0 + wt3*sv0 + wt4*(sv1*y2 - sv2*y1);
    av1 += w2s*y1 + wt3*sv1 + wt4*(sv2*y0 - sv0*y2);
    av2 += w2s*y2 + wt3*sv2 + wt4*(sv0*y1 - sv1*y0);
  }
  size_t ro = (size_t)cur*256 + lane;
  atomicAdd(&agg[ro],     as_);
  atomicAdd(&agg[ro+64],  av0);
  atomicAdd(&agg[ro+128], av1);
  atomicAdd(&agg[ro+192], av2);
}

// ---------------- node post-pass: 4 nodes per wave (r7-proven) ----------------
__global__ __launch_bounds__(256) void k_node_post(
  const float* __restrict__ node_feats, const int* __restrict__ specie,
  const float* __restrict__ agg,
  const float* __restrict__ Wrst, const float* __restrict__ Wrvt,
  const float* __restrict__ W_out_s, const float* __restrict__ W_out_v,
  const float* __restrict__ W_prod_s, const float* __restrict__ W_prod_v,
  const float* __restrict__ W_lin_s, const float* __restrict__ W_lin_v,
  const float* __restrict__ W_read, float* __restrict__ out_node,
  float* __restrict__ out_feats)
{
  __shared__ float shA[16][4][64];
  __shared__ float shS[16][4][64];   // node_feats first, reused for p_s/p_v
  int wave = threadIdx.x >> 6, lane = threadIdx.x & 63;
  int nb = blockIdx.x*16 + wave*4;
  #pragma unroll
  for(int k=0;k<4;++k){
    int nd = wave*4 + k;
    size_t o = (size_t)(nb+k)*256 + lane;
    shA[nd][0][lane] = agg[o]      * (1.f/16.f);
    shA[nd][1][lane] = agg[o+64]   * (1.f/16.f);
    shA[nd][2][lane] = agg[o+128]  * (1.f/16.f);
    shA[nd][3][lane] = agg[o+192]  * (1.f/16.f);
    float4 nf = *(const float4*)(node_feats + (size_t)((nb+k)*64 + lane)*4);
    shS[nd][0][lane]=nf.x; shS[nd][1][lane]=nf.y; shS[nd][2][lane]=nf.z; shS[nd][3][lane]=nf.w;
  }
  int spec[4];
  #pragma unroll
  for(int k=0;k<4;++k) spec[k] = specie[nb+k];
  __syncthreads();
  float a_s[4]={0,0,0,0}, a0[4]={0,0,0,0}, a1[4]={0,0,0,0}, a2[4]={0,0,0,0};
  float r_s[4]={0,0,0,0}, r0[4]={0,0,0,0}, r1[4]={0,0,0,0}, r2[4]={0,0,0,0};
  for(int f=0; f<64; ++f){
    float wos = W_out_s[f*64+lane], wov = W_out_v[f*64+lane];
    #pragma unroll
    for(int k=0;k<4;++k){
      int nd = wave*4 + k;
      a_s[k] = fmaf(shA[nd][0][f], wos, a_s[k]);
      a0[k]  = fmaf(shA[nd][1][f], wov, a0[k]);
      a1[k]  = fmaf(shA[nd][2][f], wov, a1[k]);
      a2[k]  = fmaf(shA[nd][3][f], wov, a2[k]);
    }
    #pragma unroll
    for(int k=0;k<4;++k){
      int nd = wave*4 + k;
      float wrs = Wrst[spec[k]*4096 + f*64 + lane];
      float wrv = Wrvt[spec[k]*4096 + f*64 + lane];
      r_s[k] = fmaf(shS[nd][0][f], wrs, r_s[k]);
      r0[k]  = fmaf(shS[nd][1][f], wrv, r0[k]);
      r1[k]  = fmaf(shS[nd][2][f], wrv, r1[k]);
      r2[k]  = fmaf(shS[nd][3][f], wrv, r2[k]);
    }
  }
  __syncthreads();
  #pragma unroll
  for(int k=0;k<4;++k){
    int nd = wave*4 + k;
    float A_s = a_s[k]*0.125f, A0 = a0[k]*0.125f, A1 = a1[k]*0.125f, A2 = a2[k]*0.125f;
    float vv = A0*A0 + A1*A1 + A2*A2;
    float as2 = A_s*A_s;
    const float* Wp = W_prod_s + spec[k]*320;
    float p_s = Wp[lane]*A_s + Wp[64+lane]*as2 + Wp[128+lane]*as2*A_s
              + Wp[192+lane]*vv + Wp[256+lane]*A_s*vv;
    const float* Wq = W_prod_v + spec[k]*256;
    float coef = Wq[lane] + Wq[64+lane]*A_s + Wq[128+lane]*as2 + Wq[192+lane]*vv;
    shS[nd][0][lane] = p_s;
    shS[nd][1][lane] = coef*A0;
    shS[nd][2][lane] = coef*A1;
    shS[nd][3][lane] = coef*A2;
  }
  __syncthreads();
  float lfs[4]={0,0,0,0}, lf0[4]={0,0,0,0}, lf1[4]={0,0,0,0}, lf2[4]={0,0,0,0};
  for(int f=0; f<64; ++f){
    float wls = W_lin_s[f*64+lane], wlv = W_lin_v[f*64+lane];
    #pragma unroll
    for(int k=0;k<4;++k){
      int nd = wave*4 + k;
      lfs[k] = fmaf(shS[nd][0][f], wls, lfs[k]);
      lf0[k] = fmaf(shS[nd][1][f], wlv, lf0[k]);
      lf1[k] = fmaf(shS[nd][2][f], wlv, lf1[k]);
      lf2[k] = fmaf(shS[nd][3][f], wlv, lf2[k]);
    }
  }
  float wr = W_read[lane];
  #pragma unroll
  for(int k=0;k<4;++k){
    int n = nb + k;
    float FS = lfs[k]*0.125f + r_s[k]*0.125f;
    float F0 = lf0[k]*0.125f + r0[k]*0.125f;
    float F1 = lf1[k]*0.125f + r1[k]*0.125f;
    float F2 = lf2[k]*0.125f + r2[k]*0.125f;
    float x = FS * wr;
    #pragma unroll
    for(int off=32; off; off>>=1) x += __shfl_down(x, off);
    if(lane==0) out_node[n] = x*0.125f;
    float4 o4; o4.x=FS; o4.y=F0; o4.z=F1; o4.w=F2;
    *(float4*)(out_feats + (size_t)(n*64+lane)*4) = o4;
  }
}

extern "C" void kernel_launch(void* const* d_in, const int* in_sizes, int n_in,
                              void* d_out, int out_size, void* d_ws, size_t ws_size,
                              hipStream_t stream) {
  const float* vectors    = (const float*)d_in[0];
  const float* node_feats = (const float*)d_in[1];
  const int*   node_specie= (const int*)  d_in[2];
  const float* radial     = (const float*)d_in[3];
  const int*   senders    = (const int*)  d_in[4];
  const int*   receivers  = (const int*)  d_in[5];
  const float* W_res_s    = (const float*)d_in[6];
  const float* W_res_v    = (const float*)d_in[7];
  const float* W_in_s     = (const float*)d_in[8];
  const float* W_in_v     = (const float*)d_in[9];
  const float* mlp_w1     = (const float*)d_in[10];
  const float* mlp_w2     = (const float*)d_in[11];
  const float* W_out_s    = (const float*)d_in[12];
  const float* W_out_v    = (const float*)d_in[13];
  const float* W_prod_s   = (const float*)d_in[14];
  const float* W_prod_v   = (const float*)d_in[15];
  const float* W_lin_s    = (const float*)d_in[16];
  const float* W_lin_v    = (const float*)d_in[17];
  const float* W_read     = (const float*)d_in[18];

  float* ws   = (float*)d_ws;
  float* h    = ws;                          // 4*NF floats, [(n*64+lane)*4+c]
  float* agg  = ws + 4*(size_t)NF;           // 4*NF floats, [n*256 + c*64 + lane]
  float* Wrst = ws + 8*(size_t)NF;           // 40960
  float* Wrvt = Wrst + 40960;                // 40960
  float* rec  = Wrvt + 40960;                // 16*NE floats (64 B per edge)
  float* w2r  = rec + 16*(size_t)NE;         // 32768 floats (packed mlp_w2)
  int*   rank   = (int*)(w2r + 32768);       // NE
  int*   offset = rank + NE;                 // NN+1
  int*   count  = offset + NN + 1;           // NN

  hipMemsetAsync(agg,   0, (size_t)4*NF*sizeof(float), stream);
  hipMemsetAsync(count, 0, (size_t)NN*sizeof(int), stream);
  k_pre<<<2500, 256, 0, stream>>>(node_feats, W_in_s, W_in_v, h,
                                  receivers, count, rank,
                                  W_res_s, W_res_v, Wrst, Wrvt,
                                  mlp_w2, w2r);
  k_scan   <<<1,     1024, 0, stream>>>(count, offset);
  k_scatter<<<NE/256, 256, 0, stream>>>(senders, receivers, vectors, radial,
                                        offset, rank, rec);
  k_edge<<<NE/64, 256, 0, stream>>>(rec, mlp_w1, w2r, h, agg);
  k_node_post<<<NN/16, 256, 0, stream>>>(node_feats, node_specie, agg,
                                         Wrst, Wrvt, W_out_s, W_out_v,
                                         W_prod_s, W_prod_v, W_lin_s, W_lin_v,
                                         W_read, (float*)d_out, (float*)d_out + NN);
}

// Round 11
// 444.532 us; speedup vs baseline: 1.1165x; 1.0620x over previous
//
#include <hip/hip_runtime.h>
#include <math.h>

#define NN 20000
#define NE 320000
#define NF (NN*64)
#define TB 16

typedef float v2f __attribute__((ext_vector_type(2)));

#if __has_builtin(__builtin_elementwise_fma)
#define PKFMA(a,b,c) __builtin_elementwise_fma(a,b,c)
#else
static __device__ __forceinline__ v2f PKFMA(v2f a, v2f b, v2f c){
  v2f r; r.x = fmaf(a.x,b.x,c.x); r.y = fmaf(a.y,b.y,c.y); return r;
}
#endif

// ---------------- fused front-end (r10-exact: measured-best aux) ----------------
// blocks 0..1249   : node_pre, 4 nodes/wave
// blocks 1250..2499: receiver hist+rank; b<160 also residual-W transpose;
//                    b in [160,288) also w2 repack (kept to preserve the exact
//                    measured aux configuration; k_edge does not consume it)
__global__ __launch_bounds__(256) void k_pre(
    const float* __restrict__ node_feats, const float* __restrict__ W_in_s,
    const float* __restrict__ W_in_v, float* __restrict__ h,
    const int* __restrict__ receivers, int* __restrict__ count, int* __restrict__ rank,
    const float* __restrict__ Ws, const float* __restrict__ Wv,
    float* __restrict__ Wst, float* __restrict__ Wvt,
    const float* __restrict__ w2, float* __restrict__ w2r)
{
  __shared__ float sh[16][4][64];
  if(blockIdx.x >= 1250){
    int b = blockIdx.x - 1250;
    int e = b*256 + threadIdx.x;
    rank[e] = atomicAdd(&count[receivers[e]], 1);
    if(b < 160){
      int i = b*256 + threadIdx.x;   // 0..40959
      int spec = i >> 12;
      int g = (i >> 6) & 63;
      int f = i & 63;
      Wst[spec*4096 + f*64 + g] = Ws[i];
      Wvt[spec*4096 + f*64 + g] = Wv[i];
    } else if(b < 288){
      int i = (b-160)*256 + threadIdx.x;  // 0..32767
      int hh = i >> 9;
      int r  = i & 511;
      int ln = r >> 3;
      int j  = r & 7;
      w2r[i] = (j < 5) ? w2[hh*320 + j*64 + ln] : 0.f;
    }
    return;
  }
  int wave = threadIdx.x >> 6, lane = threadIdx.x & 63;
  int nb = blockIdx.x*16 + wave*4;
  #pragma unroll
  for(int k=0;k<4;++k){
    int nd = wave*4 + k;
    float4 nf = *(const float4*)(node_feats + (size_t)((nb+k)*64 + lane)*4);
    sh[nd][0][lane]=nf.x; sh[nd][1][lane]=nf.y; sh[nd][2][lane]=nf.z; sh[nd][3][lane]=nf.w;
  }
  __syncthreads();
  float as[4]={0,0,0,0}, a0[4]={0,0,0,0}, a1[4]={0,0,0,0}, a2[4]={0,0,0,0};
  for(int f=0; f<64; ++f){
    float ws = W_in_s[f*64+lane], wv = W_in_v[f*64+lane];
    #pragma unroll
    for(int k=0;k<4;++k){
      int nd = wave*4 + k;
      as[k] = fmaf(sh[nd][0][f], ws, as[k]);
      a0[k] = fmaf(sh[nd][1][f], wv, a0[k]);
      a1[k] = fmaf(sh[nd][2][f], wv, a1[k]);
      a2[k] = fmaf(sh[nd][3][f], wv, a2[k]);
    }
  }
  #pragma unroll
  for(int k=0;k<4;++k){
    float4 o4; o4.x = as[k]*0.125f; o4.y = a0[k]*0.125f;
    o4.z = a1[k]*0.125f; o4.w = a2[k]*0.125f;
    *(float4*)(h + (size_t)((nb+k)*64 + lane)*4) = o4;
  }
}

// ---------------- exclusive scan over 20000 counts: 1024 threads, reg-cached ----------------
__global__ __launch_bounds__(1024) void k_scan(const int* __restrict__ count,
                                               int* __restrict__ offset)
{
  __shared__ int part[1024];
  int t = threadIdx.x;
  const int PER = 20;                      // 1024*20 = 20480 >= NN
  int base = t*PER;
  int loc[PER];
  int s = 0;
  #pragma unroll
  for(int i=0;i<PER;++i){
    int idx = base+i;
    int v = (idx < NN) ? count[idx] : 0;
    loc[i] = v; s += v;
  }
  part[t] = s;
  __syncthreads();
  for(int off=1; off<1024; off<<=1){
    int v = (t>=off) ? part[t-off] : 0;
    __syncthreads();
    part[t] += v;
    __syncthreads();
  }
  int run = t ? part[t-1] : 0;
  #pragma unroll
  for(int i=0;i<PER;++i){
    int idx = base+i;
    if(idx < NN) offset[idx] = run;
    run += loc[i];
  }
  if(t==1023) offset[NN] = part[1023];
}

// Scatter edge data into one 64-B record per edge (receiver-sorted).
// rec layout (16 floats): [0..2]=yhat, [3]=snd(bits), [4..11]=rad, [12]=rcv(bits), [13..15]=pad
__global__ __launch_bounds__(256) void k_scatter(
    const int* __restrict__ senders, const int* __restrict__ receivers,
    const float* __restrict__ vectors, const float* __restrict__ radial,
    const int* __restrict__ offset, const int* __restrict__ rank,
    float* __restrict__ rec)
{
  int e = blockIdx.x*256 + threadIdx.x;
  int r = receivers[e];
  int slot = offset[r] + rank[e];
  float vx = vectors[e*3], vy = vectors[e*3+1], vz = vectors[e*3+2];
  float rinv = rsqrtf(vx*vx + vy*vy + vz*vz + 1e-12f);
  float4 ra = *(const float4*)(radial + (size_t)e*8);
  float4 rb = *(const float4*)(radial + (size_t)e*8 + 4);
  float* rp = rec + (size_t)slot*16;
  float4 w0; w0.x = vx*rinv; w0.y = vy*rinv; w0.z = vz*rinv; w0.w = __int_as_float(senders[e]);
  float4 w3; w3.x = __int_as_float(r); w3.y = 0.f; w3.z = 0.f; w3.w = 0.f;
  *(float4*)(rp)      = w0;
  *(float4*)(rp + 4)  = ra;
  *(float4*)(rp + 8)  = rb;
  *(float4*)(rp + 12) = w3;
}

// ---------------- edge kernel: r9-exact (measured 201 us) ----------------
// agg layout: agg[node*256 + c*64 + lane]  (channel-planar: contiguous atomics)
__global__ __launch_bounds__(256) void k_edge(
    const float* __restrict__ rec,
    const float* __restrict__ mlp_w1, const float* __restrict__ mlp_w2,
    const float* __restrict__ h, float* __restrict__ agg)
{
  __shared__ float recS[4][256];        // 16 edges x 16 floats, wave-local
  __shared__ float hid[4][64][20];      // [hh][t], stride 20; reads broadcast
  int tid = threadIdx.x;
  int wave = tid >> 6, lane = tid & 63;
  int e0 = (blockIdx.x*4 + wave)*TB;

  // stage records: 1 KB per wave in one dwordx4 (wave-local LDS, lockstep-safe)
  *(float4*)&recS[wave][lane*4] = *(const float4*)(rec + (size_t)e0*16 + lane*4);

  float wl[8];
  #pragma unroll
  for(int r=0;r<8;++r) wl[r] = mlp_w1[r*64+lane];

  // hidden = silu(rad @ w1), lane = hidden unit; store transposed [hh][t]
  #pragma unroll
  for(int t=0;t<TB;++t){
    float acc = 0.f;
    #pragma unroll
    for(int r=0;r<8;++r) acc = fmaf(recS[wave][t*16+4+r], wl[r], acc);
    hid[wave][lane][t] = acc / (1.f + __expf(-acc));
  }

  // w[j][t-pair] = sum_h hid[h][t-pair] * w2[h][j*64+lane]  -- packed fp32
  v2f wv[5][8];
  #pragma unroll
  for(int j=0;j<5;++j)
    #pragma unroll
    for(int tp=0;tp<8;++tp) wv[j][tp] = (v2f){0.f, 0.f};
  const float* w2p = mlp_w2 + lane;
  for(int hh=0; hh<64; ++hh){
    float b[5];
    #pragma unroll
    for(int j=0;j<5;++j) b[j] = w2p[hh*320 + j*64];
    v2f hv[8];
    #pragma unroll
    for(int tp=0;tp<8;++tp) hv[tp] = *(const v2f*)&hid[wave][hh][2*tp];
    #pragma unroll
    for(int j=0;j<5;++j){
      v2f bb = {b[j], b[j]};
      #pragma unroll
      for(int tp=0;tp<8;++tp) wv[j][tp] = PKFMA(bb, hv[tp], wv[j][tp]);
    }
  }

  // message build + register-run accumulation; h gathered as one float4, 4-deep pipeline
  float4 hv4[4];
  #pragma unroll
  for(int p=0;p<4;++p){
    int snd = __float_as_int(recS[wave][p*16+3]);
    hv4[p] = *(const float4*)(h + (size_t)(snd*64 + lane)*4);
  }

  float as_=0.f, av0=0.f, av1=0.f, av2=0.f;
  int cur = __float_as_int(recS[wave][12]);
  #pragma unroll
  for(int t=0;t<TB;++t){
    float4 hc = hv4[t&3];
    if(t+4 < TB){
      int snd = __float_as_int(recS[wave][(t+4)*16+3]);
      hv4[t&3] = *(const float4*)(h + (size_t)(snd*64 + lane)*4);
    }
    int rcv = __float_as_int(recS[wave][t*16+12]);
    if(rcv != cur){
      size_t ro = (size_t)cur*256 + lane;
      atomicAdd(&agg[ro],     as_);
      atomicAdd(&agg[ro+64],  av0);
      atomicAdd(&agg[ro+128], av1);
      atomicAdd(&agg[ro+192], av2);
      as_=0.f; av0=0.f; av1=0.f; av2=0.f;
      cur = rcv;
    }
    float y0=recS[wave][t*16], y1=recS[wave][t*16+1], y2=recS[wave][t*16+2];
    float ss=hc.x, sv0=hc.y, sv1=hc.z, sv2=hc.w;
    float dot = sv0*y0 + sv1*y1 + sv2*y2;
    float wt0 = wv[0][t>>1][t&1], wt1 = wv[1][t>>1][t&1];
    float wt2 = wv[2][t>>1][t&1], wt3 = wv[3][t>>1][t&1], wt4 = wv[4][t>>1][t&1];
    as_ += wt0*ss + wt1*dot;
    float w2s = wt2*ss;
    av0 += w2s*y0 + wt3*sv0 + wt4*(sv1*y2 - sv2*y1);
    av1 += w2s*y1 + wt3*sv1 + wt4*(sv2*y0 - sv0*y2);
    av2 += w2s*y2 + wt3*sv2 + wt4*(sv0*y1 - sv1*y0);
  }
  size_t ro = (size_t)cur*256 + lane;
  atomicAdd(&agg[ro],     as_);
  atomicAdd(&agg[ro+64],  av0);
  atomicAdd(&agg[ro+128], av1);
  atomicAdd(&agg[ro+192], av2);
}

// ---------------- node post-pass: 4 nodes per wave (r7/r10-proven) ----------------
__global__ __launch_bounds__(256) void k_node_post(
  const float* __restrict__ node_feats, const int* __restrict__ specie,
  const float* __restrict__ agg,
  const float* __restrict__ Wrst, const float* __restrict__ Wrvt,
  const float* __restrict__ W_out_s, const float* __restrict__ W_out_v,
  const float* __restrict__ W_prod_s, const float* __restrict__ W_prod_v,
  const float* __restrict__ W_lin_s, const float* __restrict__ W_lin_v,
  const float* __restrict__ W_read, float* __restrict__ out_node,
  float* __restrict__ out_feats)
{
  __shared__ float shA[16][4][64];
  __shared__ float shS[16][4][64];   // node_feats first, reused for p_s/p_v
  int wave = threadIdx.x >> 6, lane = threadIdx.x & 63;
  int nb = blockIdx.x*16 + wave*4;
  #pragma unroll
  for(int k=0;k<4;++k){
    int nd = wave*4 + k;
    size_t o = (size_t)(nb+k)*256 + lane;
    shA[nd][0][lane] = agg[o]      * (1.f/16.f);
    shA[nd][1][lane] = agg[o+64]   * (1.f/16.f);
    shA[nd][2][lane] = agg[o+128]  * (1.f/16.f);
    shA[nd][3][lane] = agg[o+192]  * (1.f/16.f);
    float4 nf = *(const float4*)(node_feats + (size_t)((nb+k)*64 + lane)*4);
    shS[nd][0][lane]=nf.x; shS[nd][1][lane]=nf.y; shS[nd][2][lane]=nf.z; shS[nd][3][lane]=nf.w;
  }
  int spec[4];
  #pragma unroll
  for(int k=0;k<4;++k) spec[k] = specie[nb+k];
  __syncthreads();
  float a_s[4]={0,0,0,0}, a0[4]={0,0,0,0}, a1[4]={0,0,0,0}, a2[4]={0,0,0,0};
  float r_s[4]={0,0,0,0}, r0[4]={0,0,0,0}, r1[4]={0,0,0,0}, r2[4]={0,0,0,0};
  for(int f=0; f<64; ++f){
    float wos = W_out_s[f*64+lane], wov = W_out_v[f*64+lane];
    #pragma unroll
    for(int k=0;k<4;++k){
      int nd = wave*4 + k;
      a_s[k] = fmaf(shA[nd][0][f], wos, a_s[k]);
      a0[k]  = fmaf(shA[nd][1][f], wov, a0[k]);
      a1[k]  = fmaf(shA[nd][2][f], wov, a1[k]);
      a2[k]  = fmaf(shA[nd][3][f], wov, a2[k]);
    }
    #pragma unroll
    for(int k=0;k<4;++k){
      int nd = wave*4 + k;
      float wrs = Wrst[spec[k]*4096 + f*64 + lane];
      float wrv = Wrvt[spec[k]*4096 + f*64 + lane];
      r_s[k] = fmaf(shS[nd][0][f], wrs, r_s[k]);
      r0[k]  = fmaf(shS[nd][1][f], wrv, r0[k]);
      r1[k]  = fmaf(shS[nd][2][f], wrv, r1[k]);
      r2[k]  = fmaf(shS[nd][3][f], wrv, r2[k]);
    }
  }
  __syncthreads();
  #pragma unroll
  for(int k=0;k<4;++k){
    int nd = wave*4 + k;
    float A_s = a_s[k]*0.125f, A0 = a0[k]*0.125f, A1 = a1[k]*0.125f, A2 = a2[k]*0.125f;
    float vv = A0*A0 + A1*A1 + A2*A2;
    float as2 = A_s*A_s;
    const float* Wp = W_prod_s + spec[k]*320;
    float p_s = Wp[lane]*A_s + Wp[64+lane]*as2 + Wp[128+lane]*as2*A_s
              + Wp[192+lane]*vv + Wp[256+lane]*A_s*vv;
    const float* Wq = W_prod_v + spec[k]*256;
    float coef = Wq[lane] + Wq[64+lane]*A_s + Wq[128+lane]*as2 + Wq[192+lane]*vv;
    shS[nd][0][lane] = p_s;
    shS[nd][1][lane] = coef*A0;
    shS[nd][2][lane] = coef*A1;
    shS[nd][3][lane] = coef*A2;
  }
  __syncthreads();
  float lfs[4]={0,0,0,0}, lf0[4]={0,0,0,0}, lf1[4]={0,0,0,0}, lf2[4]={0,0,0,0};
  for(int f=0; f<64; ++f){
    float wls = W_lin_s[f*64+lane], wlv = W_lin_v[f*64+lane];
    #pragma unroll
    for(int k=0;k<4;++k){
      int nd = wave*4 + k;
      lfs[k] = fmaf(shS[nd][0][f], wls, lfs[k]);
      lf0[k] = fmaf(shS[nd][1][f], wlv, lf0[k]);
      lf1[k] = fmaf(shS[nd][2][f], wlv, lf1[k]);
      lf2[k] = fmaf(shS[nd][3][f], wlv, lf2[k]);
    }
  }
  float wr = W_read[lane];
  #pragma unroll
  for(int k=0;k<4;++k){
    int n = nb + k;
    float FS = lfs[k]*0.125f + r_s[k]*0.125f;
    float F0 = lf0[k]*0.125f + r0[k]*0.125f;
    float F1 = lf1[k]*0.125f + r1[k]*0.125f;
    float F2 = lf2[k]*0.125f + r2[k]*0.125f;
    float x = FS * wr;
    #pragma unroll
    for(int off=32; off; off>>=1) x += __shfl_down(x, off);
    if(lane==0) out_node[n] = x*0.125f;
    float4 o4; o4.x=FS; o4.y=F0; o4.z=F1; o4.w=F2;
    *(float4*)(out_feats + (size_t)(n*64+lane)*4) = o4;
  }
}

extern "C" void kernel_launch(void* const* d_in, const int* in_sizes, int n_in,
                              void* d_out, int out_size, void* d_ws, size_t ws_size,
                              hipStream_t stream) {
  const float* vectors    = (const float*)d_in[0];
  const float* node_feats = (const float*)d_in[1];
  const int*   node_specie= (const int*)  d_in[2];
  const float* radial     = (const float*)d_in[3];
  const int*   senders    = (const int*)  d_in[4];
  const int*   receivers  = (const int*)  d_in[5];
  const float* W_res_s    = (const float*)d_in[6];
  const float* W_res_v    = (const float*)d_in[7];
  const float* W_in_s     = (const float*)d_in[8];
  const float* W_in_v     = (const float*)d_in[9];
  const float* mlp_w1     = (const float*)d_in[10];
  const float* mlp_w2     = (const float*)d_in[11];
  const float* W_out_s    = (const float*)d_in[12];
  const float* W_out_v    = (const float*)d_in[13];
  const float* W_prod_s   = (const float*)d_in[14];
  const float* W_prod_v   = (const float*)d_in[15];
  const float* W_lin_s    = (const float*)d_in[16];
  const float* W_lin_v    = (const float*)d_in[17];
  const float* W_read     = (const float*)d_in[18];

  float* ws   = (float*)d_ws;
  float* h    = ws;                          // 4*NF floats, [(n*64+lane)*4+c]
  float* agg  = ws + 4*(size_t)NF;           // 4*NF floats, [n*256 + c*64 + lane]
  float* Wrst = ws + 8*(size_t)NF;           // 40960
  float* Wrvt = Wrst + 40960;                // 40960
  float* rec  = Wrvt + 40960;                // 16*NE floats (64 B per edge)
  float* w2r  = rec + 16*(size_t)NE;         // 32768 floats (packed mlp_w2, unused by k_edge)
  int*   rank   = (int*)(w2r + 32768);       // NE
  int*   offset = rank + NE;                 // NN+1
  int*   count  = offset + NN + 1;           // NN

  hipMemsetAsync(agg,   0, (size_t)4*NF*sizeof(float), stream);
  hipMemsetAsync(count, 0, (size_t)NN*sizeof(int), stream);
  k_pre<<<2500, 256, 0, stream>>>(node_feats, W_in_s, W_in_v, h,
                                  receivers, count, rank,
                                  W_res_s, W_res_v, Wrst, Wrvt,
                                  mlp_w2, w2r);
  k_scan   <<<1,     1024, 0, stream>>>(count, offset);
  k_scatter<<<NE/256, 256, 0, stream>>>(senders, receivers, vectors, radial,
                                        offset, rank, rec);
  k_edge<<<NE/64, 256, 0, stream>>>(rec, mlp_w1, mlp_w2, h, agg);
  k_node_post<<<NN/16, 256, 0, stream>>>(node_feats, node_specie, agg,
                                         Wrst, Wrvt, W_out_s, W_out_v,
                                         W_prod_s, W_prod_v, W_lin_s, W_lin_v,
                                         W_read, (float*)d_out, (float*)d_out + NN);
}